// Round 4
// baseline (215.271 us; speedup 1.0000x reference)
//
#include <hip/hip_runtime.h>
#include <hip/hip_bf16.h>

typedef __attribute__((ext_vector_type(8))) short short8;
typedef __attribute__((ext_vector_type(4))) float floatx4;

#define MFMA_BF16(a, b, c) __builtin_amdgcn_mfma_f32_16x16x32_bf16((a), (b), (c), 0, 0, 0)

__device__ __forceinline__ unsigned short f2bf(float f) {
    union { float f; unsigned u; } v; v.f = f;
    unsigned r = v.u + 0x7fffu + ((v.u >> 16) & 1u);
    return (unsigned short)(r >> 16);
}

// async global->LDS, 16B per lane (global_load_lds_dwordx4)
__device__ __forceinline__ void gload16(const unsigned short* g, unsigned short* l) {
    __builtin_amdgcn_global_load_lds(
        (const __attribute__((address_space(1))) unsigned int*)g,
        (__attribute__((address_space(3))) unsigned int*)l, 16, 0, 0);
}

__device__ __forceinline__ void phase_barrier() {
    __builtin_amdgcn_sched_barrier(0);
    __builtin_amdgcn_s_barrier();
    __builtin_amdgcn_sched_barrier(0);
}

// ---------------- elementwise cast f32 -> bf16 ----------------
__global__ void cast_f32_to_bf16(const float* __restrict__ src,
                                 unsigned short* __restrict__ dst, int n4) {
    int i = blockIdx.x * blockDim.x + threadIdx.x;
    int stride = gridDim.x * blockDim.x;
    for (; i < n4; i += stride) {
        float4 f = reinterpret_cast<const float4*>(src)[i];
        ushort4 o;
        o.x = f2bf(f.x); o.y = f2bf(f.y); o.z = f2bf(f.z); o.w = f2bf(f.w);
        reinterpret_cast<ushort4*>(dst)[i] = o;
    }
}

// ---------- transpose + cast: src[R][C] f32 -> dst[C][R] bf16 (R,C multiples of 32) ----------
__global__ void transpose_cast(const float* __restrict__ src,
                               unsigned short* __restrict__ dst, int R, int C) {
    __shared__ float tile[32][33];
    int c0 = blockIdx.x * 32, r0 = blockIdx.y * 32;
    int tx = threadIdx.x, ty = threadIdx.y;
#pragma unroll
    for (int i = 0; i < 32; i += 8)
        tile[ty + i][tx] = src[(long)(r0 + ty + i) * C + (c0 + tx)];
    __syncthreads();
#pragma unroll
    for (int i = 0; i < 32; i += 8)
        dst[(long)(c0 + ty + i) * R + (r0 + tx)] = f2bf(tile[tx][ty + i]);
}

// ============ 256x256 8-phase bf16 GEMM (T3+T4+T2+T5), B given as B^T ============
// C[m][n] = sum_k A[m][k] * B[n][k], bf16 out. 512 thr = 8 waves (2M x 4N).
// Wave tile 128x64: rows {mh*128 + (w>>2)*64 + [0,64)}, cols {nh*128 + (w&3)*32 + [0,32)}.
// LDS: double-buffered [2][256][64] shorts per operand = 128 KiB total (dynamic).
// 16B-slot XOR swizzle (slot ^ row&7): linear gload dest + pre-swizzled source + swizzled read.
// Phases per K-tile: (mh,nh) = (0,0),(0,1),(1,1),(1,0); af kept across 2 phases, bf0 kept ph1->ph4.
// Staging: ph1: A-h1(t+1)->buf^1, ph2: B-h1(t+1)->buf^1, ph3: A-h0(t+2)->buf, ph4: B-h0(t+2)->buf.
// (ph3/ph4 targets were last ds_read in ph1, a full barrier earlier -> race-free.)
// vmcnt(4) at tile end keeps t+2's 2 half-tiles in flight; vmcnt(0) when no t+2 staging.
__global__ __launch_bounds__(512, 2) void gemm_bt_8ph(
    const unsigned short* __restrict__ A,   // [M][K] bf16
    const unsigned short* __restrict__ B,   // [N][K] bf16
    unsigned short* __restrict__ C,         // [M][N] bf16
    int M, int N, int K) {
    extern __shared__ unsigned short smem[];
    unsigned short* Al = smem;               // [2][256*64]
    unsigned short* Bl = smem + 32768;       // [2][256*64]

    const int tid = threadIdx.x;
    const int w = tid >> 6, lane = tid & 63;
    const int fr = lane & 15, fq = lane >> 4;
    const int swz = fr & 7;
    const int wr = (w >> 2) * 64;   // A-row base within half
    const int wc = (w & 3) * 32;    // B-col base within half
    const int m0 = blockIdx.y * 256, n0 = blockIdx.x * 256;
    const int T = K >> 6;           // K-tiles (BK=64); requires T >= 2

    // ---- staging map: wave w stages rows [w*16, w*16+16) of each 128-row half ----
    const int sr = (w << 4) + (lane >> 3);      // 0..127 (first gload; +8 for second)
    const int ssl = lane & 7;                   // LDS 16B slot (linear dest)
    const int swsrc = ((ssl ^ (sr & 7)) << 3);  // pre-swizzled source col (shorts)

    const unsigned short* gpA[2][2];
    const unsigned short* gpB[2][2];
    int lo[2][2];
#pragma unroll
    for (int h = 0; h < 2; h++)
#pragma unroll
        for (int s = 0; s < 2; s++) {
            int ra = m0 + h * 128 + sr + s * 8; if (ra >= M) ra = M - 1;
            int rb = n0 + h * 128 + sr + s * 8; if (rb >= N) rb = N - 1;
            gpA[h][s] = A + (long)ra * K + swsrc;
            gpB[h][s] = B + (long)rb * K + swsrc;
            lo[h][s] = (h * 128 + sr + s * 8) * 64 + ssl * 8;
        }

#define STG_A(buf, h, kt) do { \
    gload16(gpA[h][0] + (kt) * 64, Al + (buf) * 16384 + lo[h][0]); \
    gload16(gpA[h][1] + (kt) * 64, Al + (buf) * 16384 + lo[h][1]); } while (0)
#define STG_B(buf, h, kt) do { \
    gload16(gpB[h][0] + (kt) * 64, Bl + (buf) * 16384 + lo[h][0]); \
    gload16(gpB[h][1] + (kt) * 64, Bl + (buf) * 16384 + lo[h][1]); } while (0)
#define DSA(mh, mi, ks) (*reinterpret_cast<const short8*>( \
    &Ap[((mh) * 128 + wr + (mi) * 16 + fr) * 64 + ((((ks) * 4 + fq) ^ swz) * 8)]))
#define DSB(nh, ni, ks) (*reinterpret_cast<const short8*>( \
    &Bp[((nh) * 128 + wc + (ni) * 16 + fr) * 64 + ((((ks) * 4 + fq) ^ swz) * 8)]))

    floatx4 acc[8][4];
#pragma unroll
    for (int i = 0; i < 8; i++)
#pragma unroll
        for (int j = 0; j < 4; j++) acc[i][j] = (floatx4){0.f, 0.f, 0.f, 0.f};

    // ---- prologue: tile0 fully + h0/h2 of tile1 ----
    STG_A(0, 0, 0); STG_A(0, 1, 0); STG_B(0, 0, 0); STG_B(0, 1, 0);
    STG_A(1, 0, 1); STG_B(1, 0, 1);
    __builtin_amdgcn_sched_barrier(0);
    asm volatile("s_waitcnt vmcnt(4)" ::: "memory");  // tile0's 8 loads landed
    phase_barrier();

    for (int kt = 0; kt < T; ++kt) {
        const int p = kt & 1, pn = p ^ 1;
        const unsigned short* Ap = Al + p * 16384;
        const unsigned short* Bp = Bl + p * 16384;
        short8 af[4][2], bf0[2][2], bf1[2][2];

        // ---- phase 1: (mh0, nh0) ----
#pragma unroll
        for (int mi = 0; mi < 4; mi++) { af[mi][0] = DSA(0, mi, 0); af[mi][1] = DSA(0, mi, 1); }
#pragma unroll
        for (int ni = 0; ni < 2; ni++) { bf0[ni][0] = DSB(0, ni, 0); bf0[ni][1] = DSB(0, ni, 1); }
        if (kt + 1 < T) STG_A(pn, 1, kt + 1);
        phase_barrier();
        __builtin_amdgcn_s_setprio(1);
#pragma unroll
        for (int mi = 0; mi < 4; mi++)
#pragma unroll
            for (int ni = 0; ni < 2; ni++) {
                acc[mi][ni] = MFMA_BF16(af[mi][0], bf0[ni][0], acc[mi][ni]);
                acc[mi][ni] = MFMA_BF16(af[mi][1], bf0[ni][1], acc[mi][ni]);
            }
        __builtin_amdgcn_s_setprio(0);
        phase_barrier();

        // ---- phase 2: (mh0, nh1) ----
#pragma unroll
        for (int ni = 0; ni < 2; ni++) { bf1[ni][0] = DSB(1, ni, 0); bf1[ni][1] = DSB(1, ni, 1); }
        if (kt + 1 < T) STG_B(pn, 1, kt + 1);
        phase_barrier();
        __builtin_amdgcn_s_setprio(1);
#pragma unroll
        for (int mi = 0; mi < 4; mi++)
#pragma unroll
            for (int ni = 0; ni < 2; ni++) {
                acc[mi][2 + ni] = MFMA_BF16(af[mi][0], bf1[ni][0], acc[mi][2 + ni]);
                acc[mi][2 + ni] = MFMA_BF16(af[mi][1], bf1[ni][1], acc[mi][2 + ni]);
            }
        __builtin_amdgcn_s_setprio(0);
        phase_barrier();

        // ---- phase 3: (mh1, nh1) ----
#pragma unroll
        for (int mi = 0; mi < 4; mi++) { af[mi][0] = DSA(1, mi, 0); af[mi][1] = DSA(1, mi, 1); }
        if (kt + 2 < T) STG_A(p, 0, kt + 2);
        phase_barrier();
        __builtin_amdgcn_s_setprio(1);
#pragma unroll
        for (int mi = 0; mi < 4; mi++)
#pragma unroll
            for (int ni = 0; ni < 2; ni++) {
                acc[4 + mi][2 + ni] = MFMA_BF16(af[mi][0], bf1[ni][0], acc[4 + mi][2 + ni]);
                acc[4 + mi][2 + ni] = MFMA_BF16(af[mi][1], bf1[ni][1], acc[4 + mi][2 + ni]);
            }
        __builtin_amdgcn_s_setprio(0);
        phase_barrier();

        // ---- phase 4: (mh1, nh0) — af kept from ph3, bf0 kept from ph1 ----
        if (kt + 2 < T) STG_B(p, 0, kt + 2);
        phase_barrier();
        __builtin_amdgcn_s_setprio(1);
#pragma unroll
        for (int mi = 0; mi < 4; mi++)
#pragma unroll
            for (int ni = 0; ni < 2; ni++) {
                acc[4 + mi][ni] = MFMA_BF16(af[mi][0], bf0[ni][0], acc[4 + mi][ni]);
                acc[4 + mi][ni] = MFMA_BF16(af[mi][1], bf0[ni][1], acc[4 + mi][ni]);
            }
        __builtin_amdgcn_s_setprio(0);
        __builtin_amdgcn_sched_barrier(0);
        if (kt + 2 < T) asm volatile("s_waitcnt vmcnt(4)" ::: "memory");
        else            asm volatile("s_waitcnt vmcnt(0)" ::: "memory");
        phase_barrier();
    }

    // ---- epilogue: bf16 C write ----
#pragma unroll
    for (int mh = 0; mh < 2; mh++)
#pragma unroll
        for (int mi = 0; mi < 4; mi++)
#pragma unroll
            for (int rr = 0; rr < 4; rr++) {
                int row = m0 + mh * 128 + wr + mi * 16 + fq * 4 + rr;
                if (row < M) {
                    long rbase = (long)row * N + n0 + wc + fr;
#pragma unroll
                    for (int nh = 0; nh < 2; nh++)
#pragma unroll
                        for (int ni = 0; ni < 2; ni++)
                            C[rbase + nh * 128 + ni * 16] =
                                f2bf(acc[mh * 4 + mi][nh * 2 + ni][rr]);
                }
            }
#undef STG_A
#undef STG_B
#undef DSA
#undef DSB
}

// ---------------- 128x128 bf16 MFMA GEMM, BK=64, swizzled LDS, B given as B^T ----------------
template <bool OUT_BF16>
__global__ __launch_bounds__(256, 4) void gemm_bt(
    const unsigned short* __restrict__ A,   // [M][K] bf16
    const unsigned short* __restrict__ B,   // [N][K] bf16
    void* __restrict__ Cout,
    const float* __restrict__ bias,
    int M, int N, int K) {
    __shared__ __align__(16) unsigned short Alds[128 * 64];
    __shared__ __align__(16) unsigned short Blds[128 * 64];

    int tid = threadIdx.x;
    int lane = tid & 63, wave = tid >> 6;
    int m0 = blockIdx.y * 128, n0 = blockIdx.x * 128;
    int wm = (wave >> 1) * 64, wn = (wave & 1) * 64;

    floatx4 acc[4][4];
#pragma unroll
    for (int mi = 0; mi < 4; mi++)
#pragma unroll
        for (int ni = 0; ni < 4; ni++) acc[mi][ni] = (floatx4){0.f, 0.f, 0.f, 0.f};

    int srow = tid >> 3;                               // 0..31
    int scol = (((tid & 7) ^ (srow & 7)) << 3);        // swizzled source offset (shorts)
    const unsigned short* ap[4];
    const unsigned short* bp[4];
    unsigned short* la[4];
    unsigned short* lb[4];
#pragma unroll
    for (int i = 0; i < 4; i++) {
        int row = i * 32 + srow;
        int ar = m0 + row; if (ar >= M) ar = M - 1;
        ap[i] = A + (long)ar * K + scol;
        bp[i] = B + (long)(n0 + row) * K + scol;
        la[i] = &Alds[row * 64 + (tid & 7) * 8];
        lb[i] = &Blds[row * 64 + (tid & 7) * 8];
    }

    for (int k0 = 0; k0 < K; k0 += 64) {
        __syncthreads();
#pragma unroll
        for (int i = 0; i < 4; i++) gload16(ap[i] + k0, la[i]);
#pragma unroll
        for (int i = 0; i < 4; i++) gload16(bp[i] + k0, lb[i]);
        __syncthreads();

#pragma unroll
        for (int ks = 0; ks < 2; ks++) {
            int sw = ((ks * 4 + (lane >> 4)) ^ (lane & 7)) * 8;
            short8 af[4], bfr[4];
#pragma unroll
            for (int mi = 0; mi < 4; mi++)
                af[mi] = *reinterpret_cast<const short8*>(
                    &Alds[(wm + mi * 16 + (lane & 15)) * 64 + sw]);
#pragma unroll
            for (int ni = 0; ni < 4; ni++)
                bfr[ni] = *reinterpret_cast<const short8*>(
                    &Blds[(wn + ni * 16 + (lane & 15)) * 64 + sw]);
#pragma unroll
            for (int mi = 0; mi < 4; mi++)
#pragma unroll
                for (int ni = 0; ni < 4; ni++)
                    acc[mi][ni] = MFMA_BF16(af[mi], bfr[ni], acc[mi][ni]);
        }
    }

    if (OUT_BF16) {
        unsigned short* C = (unsigned short*)Cout;
#pragma unroll
        for (int mi = 0; mi < 4; mi++)
#pragma unroll
            for (int rr = 0; rr < 4; rr++) {
                int row = m0 + wm + mi * 16 + (lane >> 4) * 4 + rr;
                if (row < M) {
                    long rbase = (long)row * N + n0 + wn + (lane & 15);
#pragma unroll
                    for (int ni = 0; ni < 4; ni++)
                        C[rbase + ni * 16] = f2bf(acc[mi][ni][rr]);
                }
            }
    } else {
        float* C = (float*)Cout;
        float bv[4];
#pragma unroll
        for (int ni = 0; ni < 4; ni++) bv[ni] = bias[n0 + wn + ni * 16 + (lane & 15)];
#pragma unroll
        for (int mi = 0; mi < 4; mi++)
#pragma unroll
            for (int rr = 0; rr < 4; rr++) {
                int row = m0 + wm + mi * 16 + (lane >> 4) * 4 + rr;
                if (row < M) {
                    long rbase = (long)row * N + n0 + wn + (lane & 15);
#pragma unroll
                    for (int ni = 0; ni < 4; ni++)
                        C[rbase + ni * 16] = acc[mi][ni][rr] + bv[ni];
                }
            }
    }
}

// ---------------- fused attention: one block per (b,h) ----------------
__global__ __launch_bounds__(448, 2) void attn_kernel(
    const unsigned short* __restrict__ qkv,
    const float* __restrict__ scale,
    unsigned short* __restrict__ out) {
    const int N = 197, D3 = 2304;
    const int NT = 13;                 // 13*16 = 208 >= 197
    int b = blockIdx.x / 12, h = blockIdx.x % 12;
    int tid = threadIdx.x, lane = tid & 63, wave = tid >> 6;

    __shared__ __align__(16) unsigned short Klds[208 * 64];
    __shared__ __align__(16) unsigned short Vlds[64 * 224];
    __shared__ __align__(16) unsigned short Plds[7 * 16 * 32];

    const unsigned short* base = qkv + (long)b * N * D3 + h * 64;

    for (int idx = tid; idx < 208 * 8; idx += 448) {
        int r = idx >> 3, s = idx & 7;
        short8 v = {0, 0, 0, 0, 0, 0, 0, 0};
        if (r < N) v = *reinterpret_cast<const short8*>(base + (long)r * D3 + 768 + s * 8);
        *reinterpret_cast<short8*>(&Klds[r * 64 + (s ^ (r & 7)) * 8]) = v;
    }
    for (int idx = tid; idx < 224 * 8; idx += 448) {
        int j = idx >> 3, sg = idx & 7;
        short8 v = {0, 0, 0, 0, 0, 0, 0, 0};
        if (j < N) v = *reinterpret_cast<const short8*>(base + (long)j * D3 + 1536 + sg * 8);
        int s = j >> 3;
#pragma unroll
        for (int e = 0; e < 8; e++) {
            int d = sg * 8 + e;
            Vlds[d * 224 + (s ^ (d & 3)) * 8 + (j & 7)] = (unsigned short)v[e];
        }
    }
    __syncthreads();

    float sc = scale[h];
    unsigned short* Pw = &Plds[wave * (16 * 32)];

    for (int rtb = 0; rtb < 2; rtb++) {
        int rt = wave + rtb * 7;
        int i0 = rt * 16;
        int qrow = i0 + (lane & 15); if (qrow > N - 1) qrow = N - 1;
        const unsigned short* qp = base + (long)qrow * D3;
        short8 qf[2];
#pragma unroll
        for (int kb = 0; kb < 2; kb++)
            qf[kb] = *reinterpret_cast<const short8*>(qp + kb * 32 + (lane >> 4) * 8);

        floatx4 sf[NT];
#pragma unroll
        for (int jt = 0; jt < NT; jt++) sf[jt] = (floatx4){0.f, 0.f, 0.f, 0.f};
#pragma unroll
        for (int jt = 0; jt < NT; jt++) {
#pragma unroll
            for (int kb = 0; kb < 2; kb++) {
                int r = jt * 16 + (lane & 15);
                int slot = kb * 4 + (lane >> 4);
                short8 kf = *reinterpret_cast<const short8*>(
                    &Klds[r * 64 + (slot ^ (r & 7)) * 8]);
                sf[jt] = MFMA_BF16(qf[kb], kf, sf[jt]);
            }
        }

        int rowg[4];
        float mx[4], sm[4];
#pragma unroll
        for (int rr = 0; rr < 4; rr++) { rowg[rr] = i0 + (lane >> 4) * 4 + rr; mx[rr] = -1e30f; }
#pragma unroll
        for (int jt = 0; jt < NT; jt++) {
            int col = jt * 16 + (lane & 15);
#pragma unroll
            for (int rr = 0; rr < 4; rr++) {
                float v = sf[jt][rr] * sc;
                if (col >= N || col == rowg[rr]) v = -1e30f;
                sf[jt][rr] = v;
                mx[rr] = fmaxf(mx[rr], v);
            }
        }
#pragma unroll
        for (int rr = 0; rr < 4; rr++) {
#pragma unroll
            for (int m = 1; m <= 8; m <<= 1)
                mx[rr] = fmaxf(mx[rr], __shfl_xor(mx[rr], m, 64));
            sm[rr] = 0.f;
        }
#pragma unroll
        for (int jt = 0; jt < NT; jt++)
#pragma unroll
            for (int rr = 0; rr < 4; rr++) {
                float p = __expf(sf[jt][rr] - mx[rr]);
                sf[jt][rr] = p;
                sm[rr] += p;
            }
#pragma unroll
        for (int rr = 0; rr < 4; rr++)
#pragma unroll
            for (int m = 1; m <= 8; m <<= 1)
                sm[rr] += __shfl_xor(sm[rr], m, 64);

        floatx4 oacc[4];
#pragma unroll
        for (int dt = 0; dt < 4; dt++) oacc[dt] = (floatx4){0.f, 0.f, 0.f, 0.f};
#pragma unroll
        for (int c = 0; c < 7; c++) {
#pragma unroll
            for (int jh = 0; jh < 2; jh++) {
                int jtc = c * 2 + jh;
#pragma unroll
                for (int rr = 0; rr < 4; rr++) {
                    int row = (lane >> 4) * 4 + rr;
                    int jj = jh * 16 + (lane & 15);
                    float pv = (jtc < NT) ? sf[jtc < NT ? jtc : 0][rr] : 0.f;
                    Pw[row * 32 + ((jj >> 3) ^ (row & 3)) * 8 + (jj & 7)] = f2bf(pv);
                }
            }
            int prow = lane & 15;
            short8 pa = *reinterpret_cast<const short8*>(
                &Pw[prow * 32 + (((lane >> 4)) ^ (prow & 3)) * 8]);
#pragma unroll
            for (int dt = 0; dt < 4; dt++) {
                int d = dt * 16 + (lane & 15);
                int slot = c * 4 + (lane >> 4);
                short8 vf = *reinterpret_cast<const short8*>(
                    &Vlds[d * 224 + (slot ^ (d & 3)) * 8]);
                oacc[dt] = MFMA_BF16(pa, vf, oacc[dt]);
            }
        }

#pragma unroll
        for (int rr = 0; rr < 4; rr++) {
            int n = rowg[rr];
            if (n < N) {
                float r = 1.f / sm[rr];
                long o = ((long)b * N + n) * 768 + h * 64;
#pragma unroll
                for (int dt = 0; dt < 4; dt++)
                    out[o + dt * 16 + (lane & 15)] = f2bf(oacc[dt][rr] * r);
            }
        }
    }
}

extern "C" void kernel_launch(void* const* d_in, const int* in_sizes, int n_in,
                              void* d_out, int out_size, void* d_ws, size_t ws_size,
                              hipStream_t stream) {
    (void)in_sizes; (void)n_in; (void)out_size; (void)ws_size;
    const float* x     = (const float*)d_in[0];
    const float* scale = (const float*)d_in[1];
    const float* Wqkv  = (const float*)d_in[2];
    const float* Wout  = (const float*)d_in[3];
    const float* bout  = (const float*)d_in[4];
    float* out = (float*)d_out;

    const int M = 12608;  // 64*197
    char* ws = (char*)d_ws;
    unsigned short* x_bf   = (unsigned short*)(ws);                     // 19365888 B
    unsigned short* wqkv_t = (unsigned short*)(ws + 19365888);          //  3538944 B
    unsigned short* wout_t = (unsigned short*)(ws + 22904832);          //  1179648 B
    unsigned short* qkv    = (unsigned short*)(ws + 24084480);          // 58097664 B
    unsigned short* ao     = (unsigned short*)(ws + 82182144);          // 19365888 B

    hipFuncSetAttribute((const void*)gemm_bt_8ph,
                        hipFuncAttributeMaxDynamicSharedMemorySize, 131072);

    cast_f32_to_bf16<<<2048, 256, 0, stream>>>(x, x_bf, (M * 768) / 4);
    transpose_cast<<<dim3(2304 / 32, 768 / 32), dim3(32, 8), 0, stream>>>(Wqkv, wqkv_t, 768, 2304);
    transpose_cast<<<dim3(768 / 32, 768 / 32), dim3(32, 8), 0, stream>>>(Wout, wout_t, 768, 768);
    gemm_bt_8ph<<<dim3(2304 / 256, 50), 512, 131072, stream>>>(x_bf, wqkv_t, qkv, M, 2304, 768);
    attn_kernel<<<768, 448, 0, stream>>>(qkv, scale, ao);
    gemm_bt<false><<<dim3(768 / 128, 99), 256, 0, stream>>>(ao, wout_t, out, bout, M, 768, 768);
}

// Round 7
// 194.103 us; speedup vs baseline: 1.1091x; 1.1091x over previous
//
#include <hip/hip_runtime.h>
#include <hip/hip_bf16.h>

typedef __attribute__((ext_vector_type(8))) short short8;
typedef __attribute__((ext_vector_type(4))) float floatx4;

#define MFMA_BF16(a, b, c) __builtin_amdgcn_mfma_f32_16x16x32_bf16((a), (b), (c), 0, 0, 0)

__device__ __forceinline__ unsigned short f2bf(float f) {
    union { float f; unsigned u; } v; v.f = f;
    unsigned r = v.u + 0x7fffu + ((v.u >> 16) & 1u);
    return (unsigned short)(r >> 16);
}

// async global->LDS, 16B per lane (global_load_lds_dwordx4)
__device__ __forceinline__ void gload16(const unsigned short* g, unsigned short* l) {
    __builtin_amdgcn_global_load_lds(
        (const __attribute__((address_space(1))) unsigned int*)g,
        (__attribute__((address_space(3))) unsigned int*)l, 16, 0, 0);
}

// bijective XCD-aware block swizzle (m204): blocks on one XCD cover contiguous tiles
__device__ __forceinline__ int xcd_swizzle(int L, int nwg) {
    int q = nwg >> 3, r = nwg & 7;
    int xcd = L & 7, idx = L >> 3;
    int base = (xcd < r) ? xcd * (q + 1) : r * (q + 1) + (xcd - r) * q;
    return base + idx;
}

// ---------------- fused prep: cast x -> bf16, transpose+cast both weight mats ----------------
// blocks [0,2048): cast (grid-stride); [2048,3776): W_qkv transpose; [3776,4352): W_out transpose
__global__ __launch_bounds__(256) void prep_kernel(
    const float* __restrict__ x, unsigned short* __restrict__ x_bf,
    const float* __restrict__ Wqkv, unsigned short* __restrict__ wqkv_t,
    const float* __restrict__ Wout, unsigned short* __restrict__ wout_t) {
    int bid = blockIdx.x;
    if (bid < 2048) {
        const int n4 = (12608 * 768) / 4;
        for (int i = bid * 256 + threadIdx.x; i < n4; i += 2048 * 256) {
            float4 f = reinterpret_cast<const float4*>(x)[i];
            ushort4 o;
            o.x = f2bf(f.x); o.y = f2bf(f.y); o.z = f2bf(f.z); o.w = f2bf(f.w);
            reinterpret_cast<ushort4*>(x_bf)[i] = o;
        }
        return;
    }
    // transpose+cast src[R][C] -> dst[C][R]
    const float* src; unsigned short* dst; int R, C, bx, by;
    if (bid < 2048 + 1728) {
        int tb = bid - 2048; src = Wqkv; dst = wqkv_t; R = 768; C = 2304;
        bx = tb % 72; by = tb / 72;
    } else {
        int tb = bid - 3776; src = Wout; dst = wout_t; R = 768; C = 768;
        bx = tb % 24; by = tb / 24;
    }
    __shared__ float tile[32][33];
    int tx = threadIdx.x & 31, ty = threadIdx.x >> 5;  // 32 x 8
    int c0 = bx * 32, r0 = by * 32;
#pragma unroll
    for (int i = 0; i < 32; i += 8)
        tile[ty + i][tx] = src[(long)(r0 + ty + i) * C + (c0 + tx)];
    __syncthreads();
#pragma unroll
    for (int i = 0; i < 32; i += 8)
        dst[(long)(c0 + ty + i) * R + (r0 + tx)] = f2bf(tile[tx][ty + i]);
}

// ---------------- 128x128 bf16 MFMA GEMM, BK=64, swizzled LDS, B given as B^T ----------------
// C[m][n] = sum_k A[m][k] * B[n][k].
// LDS [128][64] shorts per operand; 16B-slot XOR-swizzle (slot ^ (row&7)):
// linear global_load_lds dest + inverse-swizzled global SOURCE + swizzled ds_read (rule #21).
// XCD-aware block swizzle (T1): contiguous tile chunk per XCD -> A-panels stay in XCD L2.
template <bool OUT_BF16>
__global__ __launch_bounds__(256, 4) void gemm_bt(
    const unsigned short* __restrict__ A,   // [M][K] bf16
    const unsigned short* __restrict__ B,   // [N][K] bf16
    void* __restrict__ Cout,
    const float* __restrict__ bias,
    int M, int N, int K) {
    __shared__ __align__(16) unsigned short Alds[128 * 64];
    __shared__ __align__(16) unsigned short Blds[128 * 64];

    int tid = threadIdx.x;
    int lane = tid & 63, wave = tid >> 6;
    int nwg = gridDim.x * gridDim.y;
    int L = blockIdx.y * gridDim.x + blockIdx.x;
    int t = xcd_swizzle(L, nwg);
    int m0 = (t / gridDim.x) * 128, n0 = (t % gridDim.x) * 128;
    int wm = (wave >> 1) * 64, wn = (wave & 1) * 64;

    floatx4 acc[4][4];
#pragma unroll
    for (int mi = 0; mi < 4; mi++)
#pragma unroll
        for (int ni = 0; ni < 4; ni++) acc[mi][ni] = (floatx4){0.f, 0.f, 0.f, 0.f};

    // staging: thread t, chunk i covers LDS row (i*32 + t>>3), 16B slot (t&7) [linear dest]
    // source k-offset is the swizzle-inverse: slot' = (t&7) ^ (row&7)
    int srow = tid >> 3;                               // 0..31
    int scol = (((tid & 7) ^ (srow & 7)) << 3);        // swizzled source offset (shorts)
    const unsigned short* ap[4];
    const unsigned short* bp[4];
    unsigned short* la[4];
    unsigned short* lb[4];
#pragma unroll
    for (int i = 0; i < 4; i++) {
        int row = i * 32 + srow;
        int ar = m0 + row; if (ar >= M) ar = M - 1;
        ap[i] = A + (long)ar * K + scol;
        bp[i] = B + (long)(n0 + row) * K + scol;
        la[i] = &Alds[row * 64 + (tid & 7) * 8];
        lb[i] = &Blds[row * 64 + (tid & 7) * 8];
    }

    for (int k0 = 0; k0 < K; k0 += 64) {
        __syncthreads();              // previous iter's reads done before overwrite
#pragma unroll
        for (int i = 0; i < 4; i++) gload16(ap[i] + k0, la[i]);
#pragma unroll
        for (int i = 0; i < 4; i++) gload16(bp[i] + k0, lb[i]);
        __syncthreads();              // drains vmcnt(0) + joins

#pragma unroll
        for (int ks = 0; ks < 2; ks++) {
            int sw = ((ks * 4 + (lane >> 4)) ^ (lane & 7)) * 8;  // swizzled read slot
            short8 af[4], bfr[4];
#pragma unroll
            for (int mi = 0; mi < 4; mi++)
                af[mi] = *reinterpret_cast<const short8*>(
                    &Alds[(wm + mi * 16 + (lane & 15)) * 64 + sw]);
#pragma unroll
            for (int ni = 0; ni < 4; ni++)
                bfr[ni] = *reinterpret_cast<const short8*>(
                    &Blds[(wn + ni * 16 + (lane & 15)) * 64 + sw]);
#pragma unroll
            for (int mi = 0; mi < 4; mi++)
#pragma unroll
                for (int ni = 0; ni < 4; ni++)
                    acc[mi][ni] = MFMA_BF16(af[mi], bfr[ni], acc[mi][ni]);
        }
    }

    // epilogue: D layout row=(lane>>4)*4+r, col=lane&15
    if (OUT_BF16) {
        unsigned short* C = (unsigned short*)Cout;
#pragma unroll
        for (int mi = 0; mi < 4; mi++)
#pragma unroll
            for (int rr = 0; rr < 4; rr++) {
                int row = m0 + wm + mi * 16 + (lane >> 4) * 4 + rr;
                if (row < M) {
                    long rbase = (long)row * N + n0 + wn + (lane & 15);
#pragma unroll
                    for (int ni = 0; ni < 4; ni++)
                        C[rbase + ni * 16] = f2bf(acc[mi][ni][rr]);
                }
            }
    } else {
        float* C = (float*)Cout;
        float bv[4];
#pragma unroll
        for (int ni = 0; ni < 4; ni++) bv[ni] = bias[n0 + wn + ni * 16 + (lane & 15)];
#pragma unroll
        for (int mi = 0; mi < 4; mi++)
#pragma unroll
            for (int rr = 0; rr < 4; rr++) {
                int row = m0 + wm + mi * 16 + (lane >> 4) * 4 + rr;
                if (row < M) {
                    long rbase = (long)row * N + n0 + wn + (lane & 15);
#pragma unroll
                    for (int ni = 0; ni < 4; ni++)
                        C[rbase + ni * 16] = acc[mi][ni][rr] + bv[ni];
                }
            }
    }
}

// ---------------- fused attention: one block per (b,h) ----------------
// qkv: [B*197][2304] bf16 rows (q|k|v each [12 heads][64]); out: [B*197][768] bf16
__global__ __launch_bounds__(448, 2) void attn_kernel(
    const unsigned short* __restrict__ qkv,
    const float* __restrict__ scale,
    unsigned short* __restrict__ out) {
    const int N = 197, D3 = 2304;
    const int NT = 13;                 // 13*16 = 208 >= 197
    int b = blockIdx.x / 12, h = blockIdx.x % 12;
    int tid = threadIdx.x, lane = tid & 63, wave = tid >> 6;

    __shared__ __align__(16) unsigned short Klds[208 * 64];
    __shared__ __align__(16) unsigned short Vlds[64 * 224];
    __shared__ __align__(16) unsigned short Plds[7 * 16 * 32];

    const unsigned short* base = qkv + (long)b * N * D3 + h * 64;

    for (int idx = tid; idx < 208 * 8; idx += 448) {
        int r = idx >> 3, s = idx & 7;
        short8 v = {0, 0, 0, 0, 0, 0, 0, 0};
        if (r < N) v = *reinterpret_cast<const short8*>(base + (long)r * D3 + 768 + s * 8);
        *reinterpret_cast<short8*>(&Klds[r * 64 + (s ^ (r & 7)) * 8]) = v;
    }
    for (int idx = tid; idx < 224 * 8; idx += 448) {
        int j = idx >> 3, sg = idx & 7;
        short8 v = {0, 0, 0, 0, 0, 0, 0, 0};
        if (j < N) v = *reinterpret_cast<const short8*>(base + (long)j * D3 + 1536 + sg * 8);
        int s = j >> 3;
#pragma unroll
        for (int e = 0; e < 8; e++) {
            int d = sg * 8 + e;
            Vlds[d * 224 + (s ^ (d & 3)) * 8 + (j & 7)] = (unsigned short)v[e];
        }
    }
    __syncthreads();

    float sc = scale[h];
    unsigned short* Pw = &Plds[wave * (16 * 32)];

    for (int rtb = 0; rtb < 2; rtb++) {
        int rt = wave + rtb * 7;
        int i0 = rt * 16;
        int qrow = i0 + (lane & 15); if (qrow > N - 1) qrow = N - 1;
        const unsigned short* qp = base + (long)qrow * D3;
        short8 qf[2];
#pragma unroll
        for (int kb = 0; kb < 2; kb++)
            qf[kb] = *reinterpret_cast<const short8*>(qp + kb * 32 + (lane >> 4) * 8);

        floatx4 sf[NT];
#pragma unroll
        for (int jt = 0; jt < NT; jt++) sf[jt] = (floatx4){0.f, 0.f, 0.f, 0.f};
#pragma unroll
        for (int jt = 0; jt < NT; jt++) {
#pragma unroll
            for (int kb = 0; kb < 2; kb++) {
                int r = jt * 16 + (lane & 15);
                int slot = kb * 4 + (lane >> 4);
                short8 kf = *reinterpret_cast<const short8*>(
                    &Klds[r * 64 + (slot ^ (r & 7)) * 8]);
                sf[jt] = MFMA_BF16(qf[kb], kf, sf[jt]);
            }
        }

        int rowg[4];
        float mx[4], sm[4];
#pragma unroll
        for (int rr = 0; rr < 4; rr++) { rowg[rr] = i0 + (lane >> 4) * 4 + rr; mx[rr] = -1e30f; }
#pragma unroll
        for (int jt = 0; jt < NT; jt++) {
            int col = jt * 16 + (lane & 15);
#pragma unroll
            for (int rr = 0; rr < 4; rr++) {
                float v = sf[jt][rr] * sc;
                if (col >= N || col == rowg[rr]) v = -1e30f;
                sf[jt][rr] = v;
                mx[rr] = fmaxf(mx[rr], v);
            }
        }
#pragma unroll
        for (int rr = 0; rr < 4; rr++) {
#pragma unroll
            for (int m = 1; m <= 8; m <<= 1)
                mx[rr] = fmaxf(mx[rr], __shfl_xor(mx[rr], m, 64));
            sm[rr] = 0.f;
        }
#pragma unroll
        for (int jt = 0; jt < NT; jt++)
#pragma unroll
            for (int rr = 0; rr < 4; rr++) {
                float p = __expf(sf[jt][rr] - mx[rr]);
                sf[jt][rr] = p;
                sm[rr] += p;
            }
#pragma unroll
        for (int rr = 0; rr < 4; rr++)
#pragma unroll
            for (int m = 1; m <= 8; m <<= 1)
                sm[rr] += __shfl_xor(sm[rr], m, 64);

        floatx4 oacc[4];
#pragma unroll
        for (int dt = 0; dt < 4; dt++) oacc[dt] = (floatx4){0.f, 0.f, 0.f, 0.f};
#pragma unroll
        for (int c = 0; c < 7; c++) {
#pragma unroll
            for (int jh = 0; jh < 2; jh++) {
                int jtc = c * 2 + jh;
#pragma unroll
                for (int rr = 0; rr < 4; rr++) {
                    int row = (lane >> 4) * 4 + rr;
                    int jj = jh * 16 + (lane & 15);
                    float pv = (jtc < NT) ? sf[jtc < NT ? jtc : 0][rr] : 0.f;
                    Pw[row * 32 + ((jj >> 3) ^ (row & 3)) * 8 + (jj & 7)] = f2bf(pv);
                }
            }
            int prow = lane & 15;
            short8 pa = *reinterpret_cast<const short8*>(
                &Pw[prow * 32 + (((lane >> 4)) ^ (prow & 3)) * 8]);
#pragma unroll
            for (int dt = 0; dt < 4; dt++) {
                int d = dt * 16 + (lane & 15);
                int slot = c * 4 + (lane >> 4);
                short8 vf = *reinterpret_cast<const short8*>(
                    &Vlds[d * 224 + (slot ^ (d & 3)) * 8]);
                oacc[dt] = MFMA_BF16(pa, vf, oacc[dt]);
            }
        }

#pragma unroll
        for (int rr = 0; rr < 4; rr++) {
            int n = rowg[rr];
            if (n < N) {
                float r = 1.f / sm[rr];
                long o = ((long)b * N + n) * 768 + h * 64;
#pragma unroll
                for (int dt = 0; dt < 4; dt++)
                    out[o + dt * 16 + (lane & 15)] = f2bf(oacc[dt][rr] * r);
            }
        }
    }
}

extern "C" void kernel_launch(void* const* d_in, const int* in_sizes, int n_in,
                              void* d_out, int out_size, void* d_ws, size_t ws_size,
                              hipStream_t stream) {
    (void)in_sizes; (void)n_in; (void)out_size; (void)ws_size;
    const float* x     = (const float*)d_in[0];
    const float* scale = (const float*)d_in[1];
    const float* Wqkv  = (const float*)d_in[2];
    const float* Wout  = (const float*)d_in[3];
    const float* bout  = (const float*)d_in[4];
    float* out = (float*)d_out;

    const int M = 12608;  // 64*197
    char* ws = (char*)d_ws;
    unsigned short* x_bf   = (unsigned short*)(ws);                     // 19365888 B
    unsigned short* wqkv_t = (unsigned short*)(ws + 19365888);          //  3538944 B
    unsigned short* wout_t = (unsigned short*)(ws + 22904832);          //  1179648 B
    unsigned short* qkv    = (unsigned short*)(ws + 24084480);          // 58097664 B
    unsigned short* ao     = (unsigned short*)(ws + 82182144);          // 19365888 B

    prep_kernel<<<4352, 256, 0, stream>>>(x, x_bf, Wqkv, wqkv_t, Wout, wout_t);
    gemm_bt<true><<<dim3(2304 / 128, 99), 256, 0, stream>>>(x_bf, wqkv_t, qkv, nullptr, M, 2304, 768);
    attn_kernel<<<768, 448, 0, stream>>>(qkv, scale, ao);
    gemm_bt<false><<<dim3(768 / 128, 99), 256, 0, stream>>>(ao, wout_t, out, bout, M, 768, 768);
}